// Round 5
// baseline (468.969 us; speedup 1.0000x reference)
//
#include <hip/hip_runtime.h>

#define N_NODES 50000
#define N_EDGES 800000
#define E_TOT   850000
#define F_IN    128
#define HC      256      // H * C_hid
#define NH      8
#define C_OUT   10
#define N_GRAPH 128
#define NBLK    49       // ceil(N_NODES / 1024)
#define K3      384      // split-precision K: [hi | hi | lo]

typedef __attribute__((ext_vector_type(8))) short bf16x8;
typedef __attribute__((ext_vector_type(4))) float f32x4;

__device__ __forceinline__ float lrelu(float x){ return x > 0.f ? x : 0.2f * x; }
__device__ __forceinline__ float elu1(float x){ return x > 0.f ? x : (__expf(x) - 1.f); }

__device__ __forceinline__ unsigned short f2bf(float f){
    unsigned int u = __float_as_uint(f);
    return (unsigned short)((u + 0x7fffu + ((u >> 16) & 1u)) >> 16);
}
__device__ __forceinline__ float bf2f(unsigned short h){
    return __uint_as_float((unsigned int)h << 16);
}
__device__ __forceinline__ unsigned int pack2(float a, float b){
    return (unsigned int)f2bf(a) | ((unsigned int)f2bf(b) << 16);
}
__device__ __forceinline__ void unp2(unsigned int p, float& a, float& b){
    a = __uint_as_float(p << 16);
    b = __uint_as_float(p & 0xffff0000u);
}

// ---- init: zero deg; build split-precision B_cat (W1^T layout); transpose W2 ----
__global__ void k_init(int* __restrict__ deg, const float* __restrict__ W1,
                       unsigned short* __restrict__ bt,
                       const float* __restrict__ W2, float* __restrict__ W2t){
    int i = blockIdx.x * 256 + threadIdx.x;
    if (i < N_NODES) deg[i] = 0;
    if (blockIdx.x >= 64 && blockIdx.x < 192){
        int k = blockIdx.x - 64;      // 0..127
        int c = threadIdx.x;          // 0..255
        float v = W1[k * HC + c];
        unsigned short hi = f2bf(v);
        unsigned short lo = f2bf(v - bf2f(hi));
        bt[(size_t)c * K3 + k]       = hi;
        bt[(size_t)c * K3 + 128 + k] = lo;
        bt[(size_t)c * K3 + 256 + k] = hi;
    }
    if (blockIdx.x == 195){
        for (int j = threadIdx.x; j < HC * C_OUT; j += 256){
            int k = j / C_OUT, c = j % C_OUT;
            W2t[c * HC + k] = W2[j];
        }
    }
}

// ---- prep: x -> A_cat [N][384] bf16 = [hi | hi | lo] ----
__global__ void k_prep(const float* __restrict__ x, unsigned int* __restrict__ acat32){
    int t = blockIdx.x * 256 + threadIdx.x;   // one thread per 2 floats
    if (t >= N_NODES * 64) return;
    int r = t >> 6, kk = t & 63;
    float2 v = ((const float2*)x)[t];
    unsigned short h0 = f2bf(v.x), h1 = f2bf(v.y);
    unsigned int hip = (unsigned int)h0 | ((unsigned int)h1 << 16);
    unsigned int lop = pack2(v.x - bf2f(h0), v.y - bf2f(h1));
    acat32[(size_t)r * 192 + kk]       = hip;
    acat32[(size_t)r * 192 + 64 + kk]  = hip;
    acat32[(size_t)r * 192 + 128 + kk] = lop;
}

// ---- GEMM1 via MFMA: xh1 = x @ W1 (split-precision bf16, fp32 accum) ----
// block = 4 waves; wave w owns rows m0..m0+15; full N=256 per wave.
// A frag: A[m=lane&15][k=quad*8+j]; B frag: B[n=lane&15][k=quad*8+j] (B^T rows);
// C/D: col=lane&15, row=quad*4+reg.  Scores computed exactly from fp32 acc.
__global__ __launch_bounds__(256) void k_gemm1m(const unsigned short* __restrict__ acat,
                                                const unsigned short* __restrict__ bt,
                                                const float* __restrict__ atts,
                                                const float* __restrict__ attd,
                                                unsigned short* __restrict__ xhb,
                                                float* __restrict__ a_s,
                                                float* __restrict__ a_d){
    const int wave = threadIdx.x >> 6, lane = threadIdx.x & 63;
    const int quad = lane >> 4, lidx = lane & 15;
    const int m0 = blockIdx.x * 64 + wave * 16;
    int arow = m0 + lidx; if (arow >= N_NODES) arow = N_NODES - 1;

    bf16x8 afrag[12];
    const uint4* abase = (const uint4*)(acat + (size_t)arow * K3); // 48 uint4 per row
    #pragma unroll
    for (int ks = 0; ks < 12; ks++){
        uint4 t = abase[ks * 4 + quad];
        afrag[ks] = __builtin_bit_cast(bf16x8, t);
    }

    const uint4* bbase = (const uint4*)bt;
    for (int h = 0; h < NH; h++){
        float ss[4] = {0.f,0.f,0.f,0.f}, dd[4] = {0.f,0.f,0.f,0.f};
        #pragma unroll
        for (int sub = 0; sub < 2; sub++){
            int n = h * 2 + sub;
            int col = n * 16 + lidx;
            f32x4 acc = {0.f, 0.f, 0.f, 0.f};
            const uint4* bcol = bbase + (size_t)col * 48 + quad;
            #pragma unroll
            for (int ks = 0; ks < 12; ks++){
                bf16x8 bf = __builtin_bit_cast(bf16x8, bcol[ks * 4]);
                acc = __builtin_amdgcn_mfma_f32_16x16x32_bf16(afrag[ks], bf, acc, 0, 0, 0);
            }
            float sv = atts[col], dv = attd[col];
            #pragma unroll
            for (int reg = 0; reg < 4; reg++){
                int r = m0 + quad * 4 + reg;
                if (r < N_NODES) xhb[(size_t)r * HC + col] = f2bf(acc[reg]);
                ss[reg] += acc[reg] * sv;
                dd[reg] += acc[reg] * dv;
            }
        }
        #pragma unroll
        for (int reg = 0; reg < 4; reg++){
            float s = ss[reg], d = dd[reg];
            s += __shfl_xor(s, 1, 64); s += __shfl_xor(s, 2, 64);
            s += __shfl_xor(s, 4, 64); s += __shfl_xor(s, 8, 64);
            d += __shfl_xor(d, 1, 64); d += __shfl_xor(d, 2, 64);
            d += __shfl_xor(d, 4, 64); d += __shfl_xor(d, 8, 64);
            if (lidx == 0){
                int r = m0 + quad * 4 + reg;
                if (r < N_NODES){
                    a_s[(size_t)r * NH + h] = s;
                    a_d[(size_t)r * NH + h] = d;
                }
            }
        }
    }
}

// ---- CSR build: degree histogram ----
__global__ void k_deg(const int* __restrict__ ei, int* __restrict__ deg){
    int e = blockIdx.x * 256 + threadIdx.x;
    if (e >= E_TOT) return;
    int dst = (e < N_EDGES) ? ei[N_EDGES + e] : (e - N_EDGES);
    atomicAdd(deg + dst, 1);
}

// ---- per-1024-chunk sums ----
__global__ void k_bsum(const int* __restrict__ deg, int* __restrict__ bsum){
    int b = blockIdx.x;
    int v = 0;
    for (int i = threadIdx.x; i < 1024; i += 256){
        int idx = b * 1024 + i;
        if (idx < N_NODES) v += deg[idx];
    }
    #pragma unroll
    for (int off = 1; off < 64; off <<= 1) v += __shfl_xor(v, off, 64);
    __shared__ int sd[4];
    if ((threadIdx.x & 63) == 0) sd[threadIdx.x >> 6] = v;
    __syncthreads();
    if (threadIdx.x == 0) bsum[b] = sd[0] + sd[1] + sd[2] + sd[3];
}

// ---- scan of chunk sums (single wave) ----
__global__ void k_scanb(const int* __restrict__ bsum, int* __restrict__ bexcl, int* __restrict__ rowp){
    int l = threadIdx.x;            // 64 threads
    int v = (l < NBLK) ? bsum[l] : 0;
    int incl = v;
    #pragma unroll
    for (int off = 1; off < 64; off <<= 1){
        int t = __shfl_up(incl, off, 64);
        if (l >= off) incl += t;
    }
    if (l < NBLK) bexcl[l] = incl - v;
    if (l == 0) rowp[N_NODES] = E_TOT;
}

// ---- per-chunk Hillis-Steele scan -> row_ptr, cursor ----
__global__ __launch_bounds__(1024) void k_scan(const int* __restrict__ deg, const int* __restrict__ bexcl,
                                               int* __restrict__ rowp, int* __restrict__ cur){
    __shared__ int sd[1024];
    int b = blockIdx.x;
    int i = b * 1024 + threadIdx.x;
    int v = (i < N_NODES) ? deg[i] : 0;
    sd[threadIdx.x] = v;
    __syncthreads();
    for (int off = 1; off < 1024; off <<= 1){
        int t = (threadIdx.x >= off) ? sd[threadIdx.x - off] : 0;
        __syncthreads();
        sd[threadIdx.x] += t;
        __syncthreads();
    }
    if (i < N_NODES){
        int excl = sd[threadIdx.x] - v + bexcl[b];
        rowp[i] = excl;
        cur[i]  = excl;
    }
}

// ---- scatter edges into CSR (src values) ----
__global__ void k_scatter(const int* __restrict__ ei, int* __restrict__ cur, int* __restrict__ col){
    int e = blockIdx.x * 256 + threadIdx.x;
    if (e >= E_TOT) return;
    int s, d;
    if (e < N_EDGES){ s = ei[e]; d = ei[N_EDGES + e]; }
    else { s = e - N_EDGES; d = s; }
    int slot = atomicAdd(cur + d, 1);
    col[slot] = s;
}

// ---- layer-1 aggregation: wave per dst node; bf16 message gather, fp32 out ----
__global__ __launch_bounds__(256) void k_agg1(const unsigned short* __restrict__ xhb,
                                              const float* __restrict__ a_s, const float* __restrict__ a_d,
                                              const int* __restrict__ rowp, const int* __restrict__ col,
                                              const float* __restrict__ bias, float* __restrict__ h1){
    int wave = threadIdx.x >> 6, lane = threadIdx.x & 63;
    int n = blockIdx.x * 4 + wave;
    if (n >= N_NODES) return;
    int h = lane >> 3;
    float adh = a_d[(size_t)n * NH + h];
    int s0 = rowp[n], s1 = rowp[n + 1];
    const uint2* xv = (const uint2*)xhb;   // row = 64 uint2
    float ax = 0.f, ay = 0.f, az = 0.f, aw = 0.f;
    float den = 0.f;
    for (int idx = s0; idx < s1; idx++){
        int s = col[idx];
        float w = __expf(lrelu(a_s[(size_t)s * NH + h] + adh));
        den += w;
        uint2 p = xv[(size_t)s * 64 + lane];
        float v0, v1, v2, v3;
        unp2(p.x, v0, v1); unp2(p.y, v2, v3);
        ax += w * v0; ay += w * v1; az += w * v2; aw += w * v3;
    }
    float rden = 1.f / den;
    float4 bb = ((const float4*)bias)[lane];
    float4 r;
    r.x = elu1(ax * rden + bb.x);
    r.y = elu1(ay * rden + bb.y);
    r.z = elu1(az * rden + bb.z);
    r.w = elu1(aw * rden + bb.w);
    ((float4*)h1)[(size_t)n * 64 + lane] = r;
}

// ---- layer-2 projection + attention scalars: wave per node (fp32 h1) ----
__global__ __launch_bounds__(256) void k_gemm2(const float* __restrict__ h1, const float* __restrict__ W2t,
                                               const float* __restrict__ atts, const float* __restrict__ attd,
                                               float* __restrict__ xh2, float* __restrict__ a_s, float* __restrict__ a_d){
    int wave = threadIdx.x >> 6, lane = threadIdx.x & 63;
    int n = blockIdx.x * 4 + wave;
    if (n >= N_NODES) return;
    float4 hv = ((const float4*)h1)[(size_t)n * 64 + lane];
    float acc[C_OUT];
    #pragma unroll
    for (int c = 0; c < C_OUT; c++){
        float4 w = ((const float4*)(W2t + c * HC))[lane];
        acc[c] = hv.x*w.x + hv.y*w.y + hv.z*w.z + hv.w*w.w;
    }
    #pragma unroll
    for (int c = 0; c < C_OUT; c++){
        #pragma unroll
        for (int off = 32; off > 0; off >>= 1) acc[c] += __shfl_xor(acc[c], off, 64);
    }
    if (lane == 0){
        float s = 0.f, d = 0.f;
        #pragma unroll
        for (int c = 0; c < C_OUT; c++){
            xh2[(size_t)n * C_OUT + c] = acc[c];
            s += acc[c] * atts[c];
            d += acc[c] * attd[c];
        }
        a_s[n] = s; a_d[n] = d;
    }
}

// ---- layer-2 aggregation + elu -> per-node h2[N,10] (no atomics) ----
__global__ __launch_bounds__(256) void k_agg2(const float* __restrict__ xh2,
                                              const float* __restrict__ a_s, const float* __restrict__ a_d,
                                              const int* __restrict__ rowp, const int* __restrict__ col,
                                              const float* __restrict__ b2,
                                              float* __restrict__ h2){
    int wave = threadIdx.x >> 6, lane = threadIdx.x & 63;
    int n = blockIdx.x * 4 + wave;
    if (n >= N_NODES) return;
    float adn = a_d[n];
    int s0 = rowp[n], s1 = rowp[n + 1];
    float acc[C_OUT] = {};
    float den = 0.f;
    for (int idx = s0 + lane; idx < s1; idx += 64){
        int s = col[idx];
        float w = __expf(lrelu(a_s[s] + adn));
        den += w;
        const float* xr = xh2 + (size_t)s * C_OUT;
        #pragma unroll
        for (int c = 0; c < C_OUT; c++) acc[c] += w * xr[c];
    }
    #pragma unroll
    for (int off = 32; off > 0; off >>= 1) den += __shfl_xor(den, off, 64);
    #pragma unroll
    for (int c = 0; c < C_OUT; c++){
        #pragma unroll
        for (int off = 32; off > 0; off >>= 1) acc[c] += __shfl_xor(acc[c], off, 64);
    }
    if (lane == 0){
        float rden = 1.f / den;
        #pragma unroll
        for (int c = 0; c < C_OUT; c++)
            h2[(size_t)n * C_OUT + c] = elu1(acc[c] * rden + b2[c]);
    }
}

// ---- pooling + log_softmax: one block per graph (batch is sorted) ----
__global__ __launch_bounds__(256) void k_pool(const float* __restrict__ h2, const int* __restrict__ batch,
                                              float* __restrict__ out){
    int g = blockIdx.x;
    int l = 0, r = N_NODES;
    while (l < r){ int m = (l + r) >> 1; if (batch[m] < g) l = m + 1; else r = m; }
    int lo = l;
    l = 0; r = N_NODES;
    while (l < r){ int m = (l + r) >> 1; if (batch[m] < g + 1) l = m + 1; else r = m; }
    int hi = l;
    float acc[C_OUT] = {};
    for (int i = lo + (int)threadIdx.x; i < hi; i += 256){
        const float* row = h2 + (size_t)i * C_OUT;
        #pragma unroll
        for (int c = 0; c < C_OUT; c++) acc[c] += row[c];
    }
    #pragma unroll
    for (int c = 0; c < C_OUT; c++){
        #pragma unroll
        for (int off = 32; off > 0; off >>= 1) acc[c] += __shfl_xor(acc[c], off, 64);
    }
    __shared__ float sd[4][C_OUT];
    int wave = threadIdx.x >> 6, lane = threadIdx.x & 63;
    if (lane == 0){
        #pragma unroll
        for (int c = 0; c < C_OUT; c++) sd[wave][c] = acc[c];
    }
    __syncthreads();
    if (threadIdx.x == 0){
        float cnt = (float)(hi - lo);
        if (cnt < 1.f) cnt = 1.f;
        float v[C_OUT];
        float m = -1e30f;
        #pragma unroll
        for (int c = 0; c < C_OUT; c++){
            v[c] = (sd[0][c] + sd[1][c] + sd[2][c] + sd[3][c]) / cnt;
            m = fmaxf(m, v[c]);
        }
        float sum = 0.f;
        #pragma unroll
        for (int c = 0; c < C_OUT; c++) sum += __expf(v[c] - m);
        float lse = m + __logf(sum);
        #pragma unroll
        for (int c = 0; c < C_OUT; c++) out[g * C_OUT + c] = v[c] - lse;
    }
}

extern "C" void kernel_launch(void* const* d_in, const int* in_sizes, int n_in,
                              void* d_out, int out_size, void* d_ws, size_t ws_size,
                              hipStream_t stream){
    const float* x    = (const float*)d_in[0];
    const int*   ei   = (const int*)d_in[1];
    const int*   batch= (const int*)d_in[2];
    const float* W1   = (const float*)d_in[3];
    const float* as1  = (const float*)d_in[4];
    const float* ad1  = (const float*)d_in[5];
    const float* b1   = (const float*)d_in[6];
    const float* W2   = (const float*)d_in[7];
    const float* as2v = (const float*)d_in[8];
    const float* ad2v = (const float*)d_in[9];
    const float* b2   = (const float*)d_in[10];
    float* out = (float*)d_out;

    char* ws = (char*)d_ws;
    size_t off = 0;
    auto alloc = [&](size_t bytes)->char*{
        char* p = ws + off;
        off = (off + bytes + 255) & ~(size_t)255;
        return p;
    };
    // union region: A_cat (bf16, 38.4 MB) lives until k_gemm1m; h1 (fp32, 51.2 MB)
    // is written by k_agg1 strictly afterwards -> alias is safe on one stream.
    char* uni = alloc((size_t)N_NODES * HC * 4);              // 51.2 MB (covers 38.4 MB A_cat)
    unsigned short* acat = (unsigned short*)uni;
    float*          h1   = (float*)uni;
    unsigned short* xhb = (unsigned short*)alloc((size_t)N_NODES * HC * 2);  // bf16 gather table
    unsigned short* bt  = (unsigned short*)alloc((size_t)HC * K3 * 2);       // B_cat 196 KB
    float* asc1 = (float*)alloc((size_t)N_NODES * NH * 4);
    float* adc1 = (float*)alloc((size_t)N_NODES * NH * 4);
    int*   deg  = (int*)alloc((size_t)N_NODES * 4);
    int*   rowp = (int*)alloc((size_t)(N_NODES + 1) * 4);
    int*   cur  = (int*)alloc((size_t)N_NODES * 4);
    int*   colb = (int*)alloc((size_t)E_TOT * 4);
    int*   bsum = (int*)alloc(64 * 4);
    int*   bexcl= (int*)alloc(64 * 4);
    float* xh2  = (float*)alloc((size_t)N_NODES * C_OUT * 4);
    float* asc2 = (float*)alloc((size_t)N_NODES * 4);
    float* adc2 = (float*)alloc((size_t)N_NODES * 4);
    float* W2t  = (float*)alloc((size_t)HC * C_OUT * 4);
    float* h2   = (float*)alloc((size_t)N_NODES * C_OUT * 4);
    (void)ws_size; (void)in_sizes; (void)n_in; (void)out_size;

    hipLaunchKernelGGL(k_init,    dim3(196),   dim3(256), 0, stream, deg, W1, bt, W2, W2t);
    hipLaunchKernelGGL(k_prep,    dim3(12500), dim3(256), 0, stream, x, (unsigned int*)acat);
    hipLaunchKernelGGL(k_gemm1m,  dim3(782),   dim3(256), 0, stream, acat, bt, as1, ad1, xhb, asc1, adc1);
    hipLaunchKernelGGL(k_deg,     dim3((E_TOT + 255)/256), dim3(256), 0, stream, ei, deg);
    hipLaunchKernelGGL(k_bsum,    dim3(NBLK),  dim3(256), 0, stream, deg, bsum);
    hipLaunchKernelGGL(k_scanb,   dim3(1),     dim3(64),  0, stream, bsum, bexcl, rowp);
    hipLaunchKernelGGL(k_scan,    dim3(NBLK),  dim3(1024),0, stream, deg, bexcl, rowp, cur);
    hipLaunchKernelGGL(k_scatter, dim3((E_TOT + 255)/256), dim3(256), 0, stream, ei, cur, colb);
    hipLaunchKernelGGL(k_agg1,    dim3((N_NODES + 3)/4), dim3(256), 0, stream, xhb, asc1, adc1, rowp, colb, b1, h1);
    hipLaunchKernelGGL(k_gemm2,   dim3((N_NODES + 3)/4), dim3(256), 0, stream, h1, W2t, as2v, ad2v, xh2, asc2, adc2);
    hipLaunchKernelGGL(k_agg2,    dim3((N_NODES + 3)/4), dim3(256), 0, stream, xh2, asc2, adc2, rowp, colb, b2, h2);
    hipLaunchKernelGGL(k_pool,    dim3(N_GRAPH), dim3(256), 0, stream, h2, batch, out);
}

// Round 6
// 374.641 us; speedup vs baseline: 1.2518x; 1.2518x over previous
//
#include <hip/hip_runtime.h>

#define N_NODES 50000
#define N_EDGES 800000
#define E_TOT   850000
#define F_IN    128
#define HC      256      // H * C_hid
#define NH      8
#define C_OUT   10
#define N_GRAPH 128
#define NBLK    49       // ceil(N_NODES / 1024)
#define K3      384      // split-precision K: [hi | hi | lo]
#define XSTRIDE 12       // xh2 row stride (10 used + 2 pad)

typedef __attribute__((ext_vector_type(8))) short bf16x8;
typedef __attribute__((ext_vector_type(4))) float f32x4;

__device__ __forceinline__ float lrelu(float x){ return x > 0.f ? x : 0.2f * x; }
__device__ __forceinline__ float elu1(float x){ return x > 0.f ? x : (__expf(x) - 1.f); }

__device__ __forceinline__ unsigned short f2bf(float f){
    unsigned int u = __float_as_uint(f);
    return (unsigned short)((u + 0x7fffu + ((u >> 16) & 1u)) >> 16);
}
__device__ __forceinline__ float bf2f(unsigned short h){
    return __uint_as_float((unsigned int)h << 16);
}
__device__ __forceinline__ unsigned int pack2(float a, float b){
    return (unsigned int)f2bf(a) | ((unsigned int)f2bf(b) << 16);
}
__device__ __forceinline__ void unp2(unsigned int p, float& a, float& b){
    a = __uint_as_float(p << 16);
    b = __uint_as_float(p & 0xffff0000u);
}

// ---- setup: x->A_cat prep, deg zero, B_cat build, W2 transpose (one launch) ----
__global__ void k_setup(const float* __restrict__ x, unsigned int* __restrict__ acat32,
                        int* __restrict__ deg,
                        const float* __restrict__ W1, unsigned short* __restrict__ bt,
                        const float* __restrict__ W2, float* __restrict__ W2t){
    int b = blockIdx.x;
    int t = b * 256 + threadIdx.x;
    if (t < N_NODES) deg[t] = 0;
    if (b < 12500){
        if (t < N_NODES * 64){
            int r = t >> 6, kk = t & 63;
            float2 v = ((const float2*)x)[t];
            unsigned short h0 = f2bf(v.x), h1 = f2bf(v.y);
            unsigned int hip = (unsigned int)h0 | ((unsigned int)h1 << 16);
            unsigned int lop = pack2(v.x - bf2f(h0), v.y - bf2f(h1));
            acat32[(size_t)r * 192 + kk]       = hip;
            acat32[(size_t)r * 192 + 64 + kk]  = hip;
            acat32[(size_t)r * 192 + 128 + kk] = lop;
        }
    } else if (b < 12628){
        int k = b - 12500;            // 0..127
        int c = threadIdx.x;          // 0..255
        float v = W1[k * HC + c];
        unsigned short hi = f2bf(v);
        unsigned short lo = f2bf(v - bf2f(hi));
        bt[(size_t)c * K3 + k]       = hi;
        bt[(size_t)c * K3 + 128 + k] = lo;
        bt[(size_t)c * K3 + 256 + k] = hi;
    } else {
        for (int j = threadIdx.x; j < HC * C_OUT; j += 256){
            int k = j / C_OUT, c = j % C_OUT;
            W2t[c * HC + k] = W2[j];
        }
    }
}

// ---- GEMM1 via MFMA: 32 rows/wave, LDS-repacked coalesced stores,
//      scores exact from fp32 accumulators ----
__global__ __launch_bounds__(256) void k_gemm1m(const unsigned short* __restrict__ acat,
                                                const unsigned short* __restrict__ bt,
                                                const float* __restrict__ atts,
                                                const float* __restrict__ attd,
                                                unsigned short* __restrict__ xhb,
                                                float* __restrict__ a_s,
                                                float* __restrict__ a_d){
    __shared__ unsigned short tile[4][32][264];   // 66 KB, bf16 C-tile per wave
    __shared__ float sc[4][32][8], dc[4][32][8];  // 8 KB, per-row per-head scores
    const int wave = threadIdx.x >> 6, lane = threadIdx.x & 63;
    const int quad = lane >> 4, lidx = lane & 15;
    const int m0 = blockIdx.x * 128 + wave * 32;
    int ar0 = m0 + lidx;      if (ar0 >= N_NODES) ar0 = N_NODES - 1;
    int ar1 = m0 + 16 + lidx; if (ar1 >= N_NODES) ar1 = N_NODES - 1;

    bf16x8 af0[12], af1[12];
    const uint4* ab0 = (const uint4*)(acat + (size_t)ar0 * K3);
    const uint4* ab1 = (const uint4*)(acat + (size_t)ar1 * K3);
    #pragma unroll
    for (int ks = 0; ks < 12; ks++){
        af0[ks] = __builtin_bit_cast(bf16x8, ab0[ks * 4 + quad]);
        af1[ks] = __builtin_bit_cast(bf16x8, ab1[ks * 4 + quad]);
    }
    const uint4* bbase = (const uint4*)bt;
    for (int h = 0; h < NH; h++){
        float ss0[4] = {0,0,0,0}, ss1[4] = {0,0,0,0};
        float dd0[4] = {0,0,0,0}, dd1[4] = {0,0,0,0};
        #pragma unroll
        for (int sub = 0; sub < 2; sub++){
            int col = h * 32 + sub * 16 + lidx;
            const uint4* bcol = bbase + (size_t)col * 48 + quad;
            f32x4 acc0 = {0.f,0.f,0.f,0.f}, acc1 = {0.f,0.f,0.f,0.f};
            #pragma unroll
            for (int ks = 0; ks < 12; ks++){
                bf16x8 bf = __builtin_bit_cast(bf16x8, bcol[ks * 4]);
                acc0 = __builtin_amdgcn_mfma_f32_16x16x32_bf16(af0[ks], bf, acc0, 0, 0, 0);
                acc1 = __builtin_amdgcn_mfma_f32_16x16x32_bf16(af1[ks], bf, acc1, 0, 0, 0);
            }
            float sv = atts[col], dv = attd[col];
            #pragma unroll
            for (int reg = 0; reg < 4; reg++){
                tile[wave][quad*4+reg][col]      = f2bf(acc0[reg]);
                tile[wave][16+quad*4+reg][col]   = f2bf(acc1[reg]);
                ss0[reg] += acc0[reg] * sv;  dd0[reg] += acc0[reg] * dv;
                ss1[reg] += acc1[reg] * sv;  dd1[reg] += acc1[reg] * dv;
            }
        }
        #pragma unroll
        for (int reg = 0; reg < 4; reg++){
            float a = ss0[reg], b = dd0[reg], c = ss1[reg], d = dd1[reg];
            a += __shfl_xor(a,1,64); a += __shfl_xor(a,2,64); a += __shfl_xor(a,4,64); a += __shfl_xor(a,8,64);
            b += __shfl_xor(b,1,64); b += __shfl_xor(b,2,64); b += __shfl_xor(b,4,64); b += __shfl_xor(b,8,64);
            c += __shfl_xor(c,1,64); c += __shfl_xor(c,2,64); c += __shfl_xor(c,4,64); c += __shfl_xor(c,8,64);
            d += __shfl_xor(d,1,64); d += __shfl_xor(d,2,64); d += __shfl_xor(d,4,64); d += __shfl_xor(d,8,64);
            if (lidx == 0){
                sc[wave][quad*4+reg][h]    = a;  dc[wave][quad*4+reg][h]    = b;
                sc[wave][16+quad*4+reg][h] = c;  dc[wave][16+quad*4+reg][h] = d;
            }
        }
    }
    __syncthreads();
    // coalesced xhb stores: 512 B per row
    for (int r = 0; r < 32; r++){
        int row = m0 + r;
        if (row < N_NODES){
            uint2 p = *(const uint2*)&tile[wave][r][lane * 4];
            ((uint2*)xhb)[(size_t)row * 64 + lane] = p;
        }
    }
    // coalesced score stores: float4 per lane
    {
        int linear = lane * 4;                 // r*8 + h, all 4 in same row
        int row = m0 + (linear >> 3);
        if (row < N_NODES){
            const float* sb = &sc[wave][0][0];
            const float* db = &dc[wave][0][0];
            float4 s4 = *(const float4*)(sb + linear);
            float4 d4 = *(const float4*)(db + linear);
            *(float4*)(a_s + (size_t)m0 * NH + linear) = s4;
            *(float4*)(a_d + (size_t)m0 * NH + linear) = d4;
        }
    }
}

// ---- CSR build: degree histogram ----
__global__ void k_deg(const int* __restrict__ ei, int* __restrict__ deg){
    int e = blockIdx.x * 256 + threadIdx.x;
    if (e >= E_TOT) return;
    int dst = (e < N_EDGES) ? ei[N_EDGES + e] : (e - N_EDGES);
    atomicAdd(deg + dst, 1);
}

// ---- per-1024-chunk sums ----
__global__ void k_bsum(const int* __restrict__ deg, int* __restrict__ bsum){
    int b = blockIdx.x;
    int v = 0;
    for (int i = threadIdx.x; i < 1024; i += 256){
        int idx = b * 1024 + i;
        if (idx < N_NODES) v += deg[idx];
    }
    #pragma unroll
    for (int off = 1; off < 64; off <<= 1) v += __shfl_xor(v, off, 64);
    __shared__ int sd[4];
    if ((threadIdx.x & 63) == 0) sd[threadIdx.x >> 6] = v;
    __syncthreads();
    if (threadIdx.x == 0) bsum[b] = sd[0] + sd[1] + sd[2] + sd[3];
}

// ---- scan of chunk sums (single wave) ----
__global__ void k_scanb(const int* __restrict__ bsum, int* __restrict__ bexcl, int* __restrict__ rowp){
    int l = threadIdx.x;            // 64 threads
    int v = (l < NBLK) ? bsum[l] : 0;
    int incl = v;
    #pragma unroll
    for (int off = 1; off < 64; off <<= 1){
        int t = __shfl_up(incl, off, 64);
        if (l >= off) incl += t;
    }
    if (l < NBLK) bexcl[l] = incl - v;
    if (l == 0) rowp[N_NODES] = E_TOT;
}

// ---- per-chunk Hillis-Steele scan -> row_ptr, cursor ----
__global__ __launch_bounds__(1024) void k_scan(const int* __restrict__ deg, const int* __restrict__ bexcl,
                                               int* __restrict__ rowp, int* __restrict__ cur){
    __shared__ int sd[1024];
    int b = blockIdx.x;
    int i = b * 1024 + threadIdx.x;
    int v = (i < N_NODES) ? deg[i] : 0;
    sd[threadIdx.x] = v;
    __syncthreads();
    for (int off = 1; off < 1024; off <<= 1){
        int t = (threadIdx.x >= off) ? sd[threadIdx.x - off] : 0;
        __syncthreads();
        sd[threadIdx.x] += t;
        __syncthreads();
    }
    if (i < N_NODES){
        int excl = sd[threadIdx.x] - v + bexcl[b];
        rowp[i] = excl;
        cur[i]  = excl;
    }
}

// ---- scatter edges into CSR (src values) ----
__global__ void k_scatter(const int* __restrict__ ei, int* __restrict__ cur, int* __restrict__ col){
    int e = blockIdx.x * 256 + threadIdx.x;
    if (e >= E_TOT) return;
    int s, d;
    if (e < N_EDGES){ s = ei[e]; d = ei[N_EDGES + e]; }
    else { s = e - N_EDGES; d = s; }
    int slot = atomicAdd(cur + d, 1);
    col[slot] = s;
}

// ---- layer-1 aggregation FUSED with layer-2 projection + scores ----
// wave per dst node; bf16 message gather (unroll x2); h1 stays in registers;
// epilogue computes xh2[n] = h1 @ W2 and layer-2 attention scalars.
__global__ __launch_bounds__(256) void k_agg1f(const unsigned short* __restrict__ xhb,
                                               const float* __restrict__ a_s, const float* __restrict__ a_d,
                                               const int* __restrict__ rowp, const int* __restrict__ colb,
                                               const float* __restrict__ b1, const float* __restrict__ W2t,
                                               const float* __restrict__ as2, const float* __restrict__ ad2,
                                               float* __restrict__ xh2, float* __restrict__ asc2,
                                               float* __restrict__ adc2){
    int wave = threadIdx.x >> 6, lane = threadIdx.x & 63;
    int n = blockIdx.x * 4 + wave;
    if (n >= N_NODES) return;
    int h = lane >> 3;
    float adh = a_d[(size_t)n * NH + h];
    int s0 = rowp[n], s1 = rowp[n + 1];
    const uint2* xv = (const uint2*)xhb;
    float ax0=0.f, ay0=0.f, az0=0.f, aw0=0.f, den0=0.f;
    float ax1=0.f, ay1=0.f, az1=0.f, aw1=0.f, den1=0.f;
    int idx = s0;
    for (; idx + 1 < s1; idx += 2){
        int sA = colb[idx], sB = colb[idx + 1];
        float aA = a_s[(size_t)sA * NH + h];
        float aB = a_s[(size_t)sB * NH + h];
        uint2 pA = xv[(size_t)sA * 64 + lane];
        uint2 pB = xv[(size_t)sB * 64 + lane];
        float wA = __expf(lrelu(aA + adh));
        float wB = __expf(lrelu(aB + adh));
        den0 += wA; den1 += wB;
        float v0, v1, v2, v3;
        unp2(pA.x, v0, v1); unp2(pA.y, v2, v3);
        ax0 += wA*v0; ay0 += wA*v1; az0 += wA*v2; aw0 += wA*v3;
        unp2(pB.x, v0, v1); unp2(pB.y, v2, v3);
        ax1 += wB*v0; ay1 += wB*v1; az1 += wB*v2; aw1 += wB*v3;
    }
    if (idx < s1){
        int sA = colb[idx];
        float wA = __expf(lrelu(a_s[(size_t)sA * NH + h] + adh));
        den0 += wA;
        uint2 pA = xv[(size_t)sA * 64 + lane];
        float v0, v1, v2, v3;
        unp2(pA.x, v0, v1); unp2(pA.y, v2, v3);
        ax0 += wA*v0; ay0 += wA*v1; az0 += wA*v2; aw0 += wA*v3;
    }
    float rden = 1.f / (den0 + den1);
    float4 bb = ((const float4*)b1)[lane];
    float4 r;
    r.x = elu1((ax0 + ax1) * rden + bb.x);
    r.y = elu1((ay0 + ay1) * rden + bb.y);
    r.z = elu1((az0 + az1) * rden + bb.z);
    r.w = elu1((aw0 + aw1) * rden + bb.w);
    // fused layer-2 projection: o[c] = h1[n] . W2[:,c]
    float o[C_OUT];
    #pragma unroll
    for (int c = 0; c < C_OUT; c++){
        float4 w = ((const float4*)(W2t + c * HC))[lane];
        float v = r.x*w.x + r.y*w.y + r.z*w.z + r.w*w.w;
        v += __shfl_xor(v, 1, 64); v += __shfl_xor(v, 2, 64); v += __shfl_xor(v, 4, 64);
        v += __shfl_xor(v, 8, 64); v += __shfl_xor(v, 16, 64); v += __shfl_xor(v, 32, 64);
        o[c] = v;
    }
    if (lane == 0){
        float s2 = 0.f, d2 = 0.f;
        #pragma unroll
        for (int c = 0; c < C_OUT; c++){ s2 += o[c] * as2[c]; d2 += o[c] * ad2[c]; }
        float* xr = xh2 + (size_t)n * XSTRIDE;
        *(float4*)(xr)     = make_float4(o[0], o[1], o[2], o[3]);
        *(float4*)(xr + 4) = make_float4(o[4], o[5], o[6], o[7]);
        *(float4*)(xr + 8) = make_float4(o[8], o[9], 0.f, 0.f);
        asc2[n] = s2; adc2[n] = d2;
    }
}

// ---- layer-2 aggregation + elu -> per-node h2[N,10] (no atomics) ----
__global__ __launch_bounds__(256) void k_agg2(const float* __restrict__ xh2,
                                              const float* __restrict__ a_s, const float* __restrict__ a_d,
                                              const int* __restrict__ rowp, const int* __restrict__ colb,
                                              const float* __restrict__ b2,
                                              float* __restrict__ h2){
    int wave = threadIdx.x >> 6, lane = threadIdx.x & 63;
    int n = blockIdx.x * 4 + wave;
    if (n >= N_NODES) return;
    float adn = a_d[n];
    int s0 = rowp[n], s1 = rowp[n + 1];
    float acc[C_OUT] = {};
    float den = 0.f;
    for (int idx = s0 + lane; idx < s1; idx += 64){
        int s = colb[idx];
        float w = __expf(lrelu(a_s[s] + adn));
        den += w;
        const float* xr = xh2 + (size_t)s * XSTRIDE;
        float4 q0 = *(const float4*)(xr);
        float4 q1 = *(const float4*)(xr + 4);
        float4 q2 = *(const float4*)(xr + 8);
        acc[0] += w*q0.x; acc[1] += w*q0.y; acc[2] += w*q0.z; acc[3] += w*q0.w;
        acc[4] += w*q1.x; acc[5] += w*q1.y; acc[6] += w*q1.z; acc[7] += w*q1.w;
        acc[8] += w*q2.x; acc[9] += w*q2.y;
    }
    #pragma unroll
    for (int off = 32; off > 0; off >>= 1) den += __shfl_xor(den, off, 64);
    #pragma unroll
    for (int c = 0; c < C_OUT; c++){
        #pragma unroll
        for (int off = 32; off > 0; off >>= 1) acc[c] += __shfl_xor(acc[c], off, 64);
    }
    if (lane == 0){
        float rden = 1.f / den;
        #pragma unroll
        for (int c = 0; c < C_OUT; c++)
            h2[(size_t)n * C_OUT + c] = elu1(acc[c] * rden + b2[c]);
    }
}

// ---- pooling + log_softmax: one block per graph (batch is sorted) ----
__global__ __launch_bounds__(256) void k_pool(const float* __restrict__ h2, const int* __restrict__ batch,
                                              float* __restrict__ out){
    int g = blockIdx.x;
    int l = 0, r = N_NODES;
    while (l < r){ int m = (l + r) >> 1; if (batch[m] < g) l = m + 1; else r = m; }
    int lo = l;
    l = 0; r = N_NODES;
    while (l < r){ int m = (l + r) >> 1; if (batch[m] < g + 1) l = m + 1; else r = m; }
    int hi = l;
    float acc[C_OUT] = {};
    for (int i = lo + (int)threadIdx.x; i < hi; i += 256){
        const float* row = h2 + (size_t)i * C_OUT;
        #pragma unroll
        for (int c = 0; c < C_OUT; c++) acc[c] += row[c];
    }
    #pragma unroll
    for (int c = 0; c < C_OUT; c++){
        #pragma unroll
        for (int off = 32; off > 0; off >>= 1) acc[c] += __shfl_xor(acc[c], off, 64);
    }
    __shared__ float sd[4][C_OUT];
    int wave = threadIdx.x >> 6, lane = threadIdx.x & 63;
    if (lane == 0){
        #pragma unroll
        for (int c = 0; c < C_OUT; c++) sd[wave][c] = acc[c];
    }
    __syncthreads();
    if (threadIdx.x == 0){
        float cnt = (float)(hi - lo);
        if (cnt < 1.f) cnt = 1.f;
        float v[C_OUT];
        float m = -1e30f;
        #pragma unroll
        for (int c = 0; c < C_OUT; c++){
            v[c] = (sd[0][c] + sd[1][c] + sd[2][c] + sd[3][c]) / cnt;
            m = fmaxf(m, v[c]);
        }
        float sum = 0.f;
        #pragma unroll
        for (int c = 0; c < C_OUT; c++) sum += __expf(v[c] - m);
        float lse = m + __logf(sum);
        #pragma unroll
        for (int c = 0; c < C_OUT; c++) out[g * C_OUT + c] = v[c] - lse;
    }
}

extern "C" void kernel_launch(void* const* d_in, const int* in_sizes, int n_in,
                              void* d_out, int out_size, void* d_ws, size_t ws_size,
                              hipStream_t stream){
    const float* x    = (const float*)d_in[0];
    const int*   ei   = (const int*)d_in[1];
    const int*   batch= (const int*)d_in[2];
    const float* W1   = (const float*)d_in[3];
    const float* as1  = (const float*)d_in[4];
    const float* ad1  = (const float*)d_in[5];
    const float* b1   = (const float*)d_in[6];
    const float* W2   = (const float*)d_in[7];
    const float* as2v = (const float*)d_in[8];
    const float* ad2v = (const float*)d_in[9];
    const float* b2   = (const float*)d_in[10];
    float* out = (float*)d_out;

    char* ws = (char*)d_ws;
    size_t off = 0;
    auto alloc = [&](size_t bytes)->char*{
        char* p = ws + off;
        off = (off + bytes + 255) & ~(size_t)255;
        return p;
    };
    unsigned short* acat = (unsigned short*)alloc((size_t)N_NODES * K3 * 2);   // 38.4 MB
    unsigned short* xhb  = (unsigned short*)alloc((size_t)N_NODES * HC * 2);   // 25.6 MB
    unsigned short* bt   = (unsigned short*)alloc((size_t)HC * K3 * 2);        // 196 KB
    float* asc1 = (float*)alloc((size_t)N_NODES * NH * 4);
    float* adc1 = (float*)alloc((size_t)N_NODES * NH * 4);
    int*   deg  = (int*)alloc((size_t)N_NODES * 4);
    int*   rowp = (int*)alloc((size_t)(N_NODES + 1) * 4);
    int*   cur  = (int*)alloc((size_t)N_NODES * 4);
    int*   colb = (int*)alloc((size_t)E_TOT * 4);
    int*   bsum = (int*)alloc(64 * 4);
    int*   bexcl= (int*)alloc(64 * 4);
    float* xh2  = (float*)alloc((size_t)N_NODES * XSTRIDE * 4);
    float* asc2 = (float*)alloc((size_t)N_NODES * 4);
    float* adc2 = (float*)alloc((size_t)N_NODES * 4);
    float* W2t  = (float*)alloc((size_t)HC * C_OUT * 4);
    float* h2   = (float*)alloc((size_t)N_NODES * C_OUT * 4);
    (void)ws_size; (void)in_sizes; (void)n_in; (void)out_size;

    hipLaunchKernelGGL(k_setup,   dim3(12629), dim3(256), 0, stream, x, (unsigned int*)acat, deg, W1, bt, W2, W2t);
    hipLaunchKernelGGL(k_gemm1m,  dim3(391),   dim3(256), 0, stream, acat, bt, as1, ad1, xhb, asc1, adc1);
    hipLaunchKernelGGL(k_deg,     dim3((E_TOT + 255)/256), dim3(256), 0, stream, ei, deg);
    hipLaunchKernelGGL(k_bsum,    dim3(NBLK),  dim3(256), 0, stream, deg, bsum);
    hipLaunchKernelGGL(k_scanb,   dim3(1),     dim3(64),  0, stream, bsum, bexcl, rowp);
    hipLaunchKernelGGL(k_scan,    dim3(NBLK),  dim3(1024),0, stream, deg, bexcl, rowp, cur);
    hipLaunchKernelGGL(k_scatter, dim3((E_TOT + 255)/256), dim3(256), 0, stream, ei, cur, colb);
    hipLaunchKernelGGL(k_agg1f,   dim3((N_NODES + 3)/4), dim3(256), 0, stream, xhb, asc1, adc1, rowp, colb, b1, W2t, as2v, ad2v, xh2, asc2, adc2);
    hipLaunchKernelGGL(k_agg2,    dim3((N_NODES + 3)/4), dim3(256), 0, stream, xh2, asc2, adc2, rowp, colb, b2, h2);
    hipLaunchKernelGGL(k_pool,    dim3(N_GRAPH), dim3(256), 0, stream, h2, batch, out);
}

// Round 7
// 320.688 us; speedup vs baseline: 1.4624x; 1.1682x over previous
//
#include <hip/hip_runtime.h>

#define N_NODES 50000
#define N_EDGES 800000
#define E_TOT   850000
#define F_IN    128
#define HC      256      // H * C_hid
#define NH      8
#define C_OUT   10
#define N_GRAPH 128
#define NBLK    49       // ceil(N_NODES / 1024)
#define XSTRIDE 16       // xh2 row stride: [o0..o9, s2, d2, pad x4] = one 64B line
#define NB_DEG  3322     // ceil(E_TOT / 256)

typedef __attribute__((ext_vector_type(8))) short bf16x8;
typedef __attribute__((ext_vector_type(4))) float f32x4;

__device__ __forceinline__ float lrelu(float x){ return x > 0.f ? x : 0.2f * x; }
__device__ __forceinline__ float elu1(float x){ return x > 0.f ? x : (__expf(x) - 1.f); }

__device__ __forceinline__ unsigned short f2bf(float f){
    unsigned int u = __float_as_uint(f);
    return (unsigned short)((u + 0x7fffu + ((u >> 16) & 1u)) >> 16);
}
__device__ __forceinline__ float bf2f(unsigned short h){
    return __uint_as_float((unsigned int)h << 16);
}
__device__ __forceinline__ void unp2(unsigned int p, float& a, float& b){
    a = __uint_as_float(p << 16);
    b = __uint_as_float(p & 0xffff0000u);
}

// ---- setup: deg histogram (deg pre-zeroed by memsetAsync) + B_cat build + W2 transpose ----
__global__ void k_setup(const int* __restrict__ ei, int* __restrict__ deg,
                        const float* __restrict__ W1, unsigned short* __restrict__ bt,
                        const float* __restrict__ W2, float* __restrict__ W2t){
    int b = blockIdx.x;
    if (b < NB_DEG){
        int e = b * 256 + threadIdx.x;
        if (e < E_TOT){
            int dst = (e < N_EDGES) ? ei[N_EDGES + e] : (e - N_EDGES);
            atomicAdd(deg + dst, 1);
        }
    } else if (b < NB_DEG + 128){
        int k = b - NB_DEG;           // 0..127
        int c = threadIdx.x;          // 0..255
        float v = W1[k * HC + c];
        unsigned short hi = f2bf(v);
        unsigned short lo = f2bf(v - bf2f(hi));
        bt[(size_t)c * 256 + k]       = hi;   // col-major: [hi(128) | lo(128)] per col
        bt[(size_t)c * 256 + 128 + k] = lo;
    } else {
        for (int j = threadIdx.x; j < HC * C_OUT; j += 256){
            int k = j / C_OUT, c = j % C_OUT;
            W2t[c * HC + k] = W2[j];
        }
    }
}

// ---- GEMM1 via MFMA: reads x directly, in-register hi/lo split (split-precision),
//      LDS-repacked coalesced stores, scores exact from fp32 accumulators ----
__global__ __launch_bounds__(256) void k_gemm1m(const float* __restrict__ x,
                                                const unsigned short* __restrict__ bt,
                                                const float* __restrict__ atts,
                                                const float* __restrict__ attd,
                                                unsigned short* __restrict__ xhb,
                                                float* __restrict__ a_s,
                                                float* __restrict__ a_d){
    __shared__ unsigned short tile[4][32][264];   // bf16 C-tile per wave
    __shared__ float sc[4][32][8], dc[4][32][8];  // per-row per-head scores
    const int wave = threadIdx.x >> 6, lane = threadIdx.x & 63;
    const int quad = lane >> 4, lidx = lane & 15;
    const int m0 = blockIdx.x * 128 + wave * 32;
    int ar0 = m0 + lidx;      if (ar0 >= N_NODES) ar0 = N_NODES - 1;
    int ar1 = m0 + 16 + lidx; if (ar1 >= N_NODES) ar1 = N_NODES - 1;

    // load x rows, split into hi/lo bf16 fragments in-register
    bf16x8 ah0[4], al0[4], ah1[4], al1[4];
    #pragma unroll
    for (int ks = 0; ks < 4; ks++){
        const float* p0 = x + (size_t)ar0 * F_IN + ks * 32 + quad * 8;
        const float* p1 = x + (size_t)ar1 * F_IN + ks * 32 + quad * 8;
        float4 u0 = *(const float4*)p0, u1 = *(const float4*)(p0 + 4);
        float4 w0 = *(const float4*)p1, w1 = *(const float4*)(p1 + 4);
        float v0[8] = {u0.x,u0.y,u0.z,u0.w,u1.x,u1.y,u1.z,u1.w};
        float v1[8] = {w0.x,w0.y,w0.z,w0.w,w1.x,w1.y,w1.z,w1.w};
        bf16x8 h0v, l0v, h1v, l1v;
        #pragma unroll
        for (int j = 0; j < 8; j++){
            unsigned short hh = f2bf(v0[j]);
            h0v[j] = (short)hh;
            l0v[j] = (short)f2bf(v0[j] - bf2f(hh));
            unsigned short hg = f2bf(v1[j]);
            h1v[j] = (short)hg;
            l1v[j] = (short)f2bf(v1[j] - bf2f(hg));
        }
        ah0[ks] = h0v; al0[ks] = l0v; ah1[ks] = h1v; al1[ks] = l1v;
    }

    const uint4* bbase = (const uint4*)bt;        // col stride = 512 B = 32 uint4
    for (int h = 0; h < NH; h++){
        float ss0[4] = {0,0,0,0}, ss1[4] = {0,0,0,0};
        float dd0[4] = {0,0,0,0}, dd1[4] = {0,0,0,0};
        #pragma unroll
        for (int sub = 0; sub < 2; sub++){
            int col = h * 32 + sub * 16 + lidx;
            const uint4* bcol = bbase + (size_t)col * 32 + quad;
            bf16x8 bh[4], bl[4];
            #pragma unroll
            for (int ks = 0; ks < 4; ks++){
                bh[ks] = __builtin_bit_cast(bf16x8, bcol[ks * 4]);
                bl[ks] = __builtin_bit_cast(bf16x8, bcol[16 + ks * 4]);
            }
            f32x4 acc0 = {0.f,0.f,0.f,0.f}, acc1 = {0.f,0.f,0.f,0.f};
            #pragma unroll
            for (int ks = 0; ks < 4; ks++){        // A_hi . B_hi
                acc0 = __builtin_amdgcn_mfma_f32_16x16x32_bf16(ah0[ks], bh[ks], acc0, 0, 0, 0);
                acc1 = __builtin_amdgcn_mfma_f32_16x16x32_bf16(ah1[ks], bh[ks], acc1, 0, 0, 0);
            }
            #pragma unroll
            for (int ks = 0; ks < 4; ks++){        // A_hi . B_lo
                acc0 = __builtin_amdgcn_mfma_f32_16x16x32_bf16(ah0[ks], bl[ks], acc0, 0, 0, 0);
                acc1 = __builtin_amdgcn_mfma_f32_16x16x32_bf16(ah1[ks], bl[ks], acc1, 0, 0, 0);
            }
            #pragma unroll
            for (int ks = 0; ks < 4; ks++){        // A_lo . B_hi
                acc0 = __builtin_amdgcn_mfma_f32_16x16x32_bf16(al0[ks], bh[ks], acc0, 0, 0, 0);
                acc1 = __builtin_amdgcn_mfma_f32_16x16x32_bf16(al1[ks], bh[ks], acc1, 0, 0, 0);
            }
            float sv = atts[col], dv = attd[col];
            #pragma unroll
            for (int reg = 0; reg < 4; reg++){
                tile[wave][quad*4+reg][col]    = f2bf(acc0[reg]);
                tile[wave][16+quad*4+reg][col] = f2bf(acc1[reg]);
                ss0[reg] += acc0[reg] * sv;  dd0[reg] += acc0[reg] * dv;
                ss1[reg] += acc1[reg] * sv;  dd1[reg] += acc1[reg] * dv;
            }
        }
        #pragma unroll
        for (int reg = 0; reg < 4; reg++){
            float a = ss0[reg], b = dd0[reg], c = ss1[reg], d = dd1[reg];
            a += __shfl_xor(a,1,64); a += __shfl_xor(a,2,64); a += __shfl_xor(a,4,64); a += __shfl_xor(a,8,64);
            b += __shfl_xor(b,1,64); b += __shfl_xor(b,2,64); b += __shfl_xor(b,4,64); b += __shfl_xor(b,8,64);
            c += __shfl_xor(c,1,64); c += __shfl_xor(c,2,64); c += __shfl_xor(c,4,64); c += __shfl_xor(c,8,64);
            d += __shfl_xor(d,1,64); d += __shfl_xor(d,2,64); d += __shfl_xor(d,4,64); d += __shfl_xor(d,8,64);
            if (lidx == 0){
                sc[wave][quad*4+reg][h]    = a;  dc[wave][quad*4+reg][h]    = b;
                sc[wave][16+quad*4+reg][h] = c;  dc[wave][16+quad*4+reg][h] = d;
            }
        }
    }
    __syncthreads();
    for (int r = 0; r < 32; r++){
        int row = m0 + r;
        if (row < N_NODES){
            uint2 p = *(const uint2*)&tile[wave][r][lane * 4];
            ((uint2*)xhb)[(size_t)row * 64 + lane] = p;
        }
    }
    {
        int linear = lane * 4;                 // r*8 + h, all 4 in same row
        int row = m0 + (linear >> 3);
        if (row < N_NODES){
            const float* sb = &sc[wave][0][0];
            const float* db = &dc[wave][0][0];
            float4 s4 = *(const float4*)(sb + linear);
            float4 d4 = *(const float4*)(db + linear);
            *(float4*)(a_s + (size_t)m0 * NH + linear) = s4;
            *(float4*)(a_d + (size_t)m0 * NH + linear) = d4;
        }
    }
}

// ---- per-1024-chunk sums ----
__global__ void k_bsum(const int* __restrict__ deg, int* __restrict__ bsum){
    int b = blockIdx.x;
    int v = 0;
    for (int i = threadIdx.x; i < 1024; i += 256){
        int idx = b * 1024 + i;
        if (idx < N_NODES) v += deg[idx];
    }
    #pragma unroll
    for (int off = 1; off < 64; off <<= 1) v += __shfl_xor(v, off, 64);
    __shared__ int sd[4];
    if ((threadIdx.x & 63) == 0) sd[threadIdx.x >> 6] = v;
    __syncthreads();
    if (threadIdx.x == 0) bsum[b] = sd[0] + sd[1] + sd[2] + sd[3];
}

// ---- scan of chunk sums (single wave) ----
__global__ void k_scanb(const int* __restrict__ bsum, int* __restrict__ bexcl, int* __restrict__ rowp){
    int l = threadIdx.x;            // 64 threads
    int v = (l < NBLK) ? bsum[l] : 0;
    int incl = v;
    #pragma unroll
    for (int off = 1; off < 64; off <<= 1){
        int t = __shfl_up(incl, off, 64);
        if (l >= off) incl += t;
    }
    if (l < NBLK) bexcl[l] = incl - v;
    if (l == 0) rowp[N_NODES] = E_TOT;
}

// ---- per-chunk Hillis-Steele scan -> row_ptr, cursor ----
__global__ __launch_bounds__(1024) void k_scan(const int* __restrict__ deg, const int* __restrict__ bexcl,
                                               int* __restrict__ rowp, int* __restrict__ cur){
    __shared__ int sd[1024];
    int b = blockIdx.x;
    int i = b * 1024 + threadIdx.x;
    int v = (i < N_NODES) ? deg[i] : 0;
    sd[threadIdx.x] = v;
    __syncthreads();
    for (int off = 1; off < 1024; off <<= 1){
        int t = (threadIdx.x >= off) ? sd[threadIdx.x - off] : 0;
        __syncthreads();
        sd[threadIdx.x] += t;
        __syncthreads();
    }
    if (i < N_NODES){
        int excl = sd[threadIdx.x] - v + bexcl[b];
        rowp[i] = excl;
        cur[i]  = excl;
    }
}

// ---- scatter edges into CSR (src values) ----
__global__ void k_scatter(const int* __restrict__ ei, int* __restrict__ cur, int* __restrict__ col){
    int e = blockIdx.x * 256 + threadIdx.x;
    if (e >= E_TOT) return;
    int s, d;
    if (e < N_EDGES){ s = ei[e]; d = ei[N_EDGES + e]; }
    else { s = e - N_EDGES; d = s; }
    int slot = atomicAdd(cur + d, 1);
    col[slot] = s;
}

// ---- layer-1 aggregation FUSED with layer-2 projection + scores ----
__global__ __launch_bounds__(256) void k_agg1f(const unsigned short* __restrict__ xhb,
                                               const float* __restrict__ a_s, const float* __restrict__ a_d,
                                               const int* __restrict__ rowp, const int* __restrict__ colb,
                                               const float* __restrict__ b1, const float* __restrict__ W2t,
                                               const float* __restrict__ as2, const float* __restrict__ ad2,
                                               float* __restrict__ xh2){
    int wave = threadIdx.x >> 6, lane = threadIdx.x & 63;
    int n = blockIdx.x * 4 + wave;
    if (n >= N_NODES) return;
    int h = lane >> 3;
    float adh = a_d[(unsigned)(n * NH + h)];
    int s0 = rowp[n], s1 = rowp[n + 1];
    const uint2* xv = (const uint2*)xhb;
    float ax0=0.f, ay0=0.f, az0=0.f, aw0=0.f, den0=0.f;
    float ax1=0.f, ay1=0.f, az1=0.f, aw1=0.f, den1=0.f;
    int idx = s0;
    for (; idx + 1 < s1; idx += 2){
        int sA = colb[idx], sB = colb[idx + 1];
        float aA = a_s[(unsigned)(sA * NH + h)];
        float aB = a_s[(unsigned)(sB * NH + h)];
        uint2 pA = xv[(unsigned)(sA * 64 + lane)];
        uint2 pB = xv[(unsigned)(sB * 64 + lane)];
        float wA = __expf(lrelu(aA + adh));
        float wB = __expf(lrelu(aB + adh));
        den0 += wA; den1 += wB;
        float v0, v1, v2, v3;
        unp2(pA.x, v0, v1); unp2(pA.y, v2, v3);
        ax0 += wA*v0; ay0 += wA*v1; az0 += wA*v2; aw0 += wA*v3;
        unp2(pB.x, v0, v1); unp2(pB.y, v2, v3);
        ax1 += wB*v0; ay1 += wB*v1; az1 += wB*v2; aw1 += wB*v3;
    }
    if (idx < s1){
        int sA = colb[idx];
        float wA = __expf(lrelu(a_s[(unsigned)(sA * NH + h)] + adh));
        den0 += wA;
        uint2 pA = xv[(unsigned)(sA * 64 + lane)];
        float v0, v1, v2, v3;
        unp2(pA.x, v0, v1); unp2(pA.y, v2, v3);
        ax0 += wA*v0; ay0 += wA*v1; az0 += wA*v2; aw0 += wA*v3;
    }
    float rden = 1.f / (den0 + den1);
    float4 bb = ((const float4*)b1)[lane];
    float4 r;
    r.x = elu1((ax0 + ax1) * rden + bb.x);
    r.y = elu1((ay0 + ay1) * rden + bb.y);
    r.z = elu1((az0 + az1) * rden + bb.z);
    r.w = elu1((aw0 + aw1) * rden + bb.w);
    // fused layer-2 projection: o[c] = h1[n] . W2[:,c]
    float o[C_OUT];
    #pragma unroll
    for (int c = 0; c < C_OUT; c++){
        float4 w = ((const float4*)(W2t + c * HC))[lane];
        float v = r.x*w.x + r.y*w.y + r.z*w.z + r.w*w.w;
        v += __shfl_xor(v, 1, 64); v += __shfl_xor(v, 2, 64); v += __shfl_xor(v, 4, 64);
        v += __shfl_xor(v, 8, 64); v += __shfl_xor(v, 16, 64); v += __shfl_xor(v, 32, 64);
        o[c] = v;
    }
    if (lane == 0){
        float s2 = 0.f, d2 = 0.f;
        #pragma unroll
        for (int c = 0; c < C_OUT; c++){ s2 += o[c] * as2[c]; d2 += o[c] * ad2[c]; }
        float* xr = xh2 + (unsigned)(n * XSTRIDE);
        *(float4*)(xr)     = make_float4(o[0], o[1], o[2], o[3]);
        *(float4*)(xr + 4) = make_float4(o[4], o[5], o[6], o[7]);
        *(float4*)(xr + 8) = make_float4(o[8], o[9], s2, d2);
    }
}

// ---- layer-2 aggregation + elu -> h2[N,10]; 16 lanes per node, 64B-line rows ----
__global__ __launch_bounds__(256) void k_agg2(const float* __restrict__ xh2,
                                              const int* __restrict__ rowp, const int* __restrict__ colb,
                                              const float* __restrict__ b2,
                                              float* __restrict__ h2){
    int grp = threadIdx.x >> 4, l16 = threadIdx.x & 15;
    int n = blockIdx.x * 16 + grp;
    if (n >= N_NODES) return;
    float adn = xh2[(unsigned)(n * XSTRIDE + 11)];
    int s0 = rowp[n], s1 = rowp[n + 1];
    float acc[C_OUT] = {};
    float den = 0.f;
    for (int idx = s0 + l16; idx < s1; idx += 16){
        int s = colb[idx];
        const float* xr = xh2 + (unsigned)(s * XSTRIDE);
        float4 q0 = *(const float4*)(xr);
        float4 q1 = *(const float4*)(xr + 4);
        float4 q2 = *(const float4*)(xr + 8);
        float w = __expf(lrelu(q2.z + adn));
        den += w;
        acc[0] += w*q0.x; acc[1] += w*q0.y; acc[2] += w*q0.z; acc[3] += w*q0.w;
        acc[4] += w*q1.x; acc[5] += w*q1.y; acc[6] += w*q1.z; acc[7] += w*q1.w;
        acc[8] += w*q2.x; acc[9] += w*q2.y;
    }
    #pragma unroll
    for (int off = 1; off < 16; off <<= 1){
        den += __shfl_xor(den, off, 64);
        #pragma unroll
        for (int c = 0; c < C_OUT; c++) acc[c] += __shfl_xor(acc[c], off, 64);
    }
    if (l16 == 0){
        float rden = 1.f / den;
        #pragma unroll
        for (int c = 0; c < C_OUT; c++)
            h2[(unsigned)(n * C_OUT + c)] = elu1(acc[c] * rden + b2[c]);
    }
}

// ---- pooling + log_softmax: one block per graph (batch is sorted) ----
__global__ __launch_bounds__(256) void k_pool(const float* __restrict__ h2, const int* __restrict__ batch,
                                              float* __restrict__ out){
    int g = blockIdx.x;
    int l = 0, r = N_NODES;
    while (l < r){ int m = (l + r) >> 1; if (batch[m] < g) l = m + 1; else r = m; }
    int lo = l;
    l = 0; r = N_NODES;
    while (l < r){ int m = (l + r) >> 1; if (batch[m] < g + 1) l = m + 1; else r = m; }
    int hi = l;
    float acc[C_OUT] = {};
    for (int i = lo + (int)threadIdx.x; i < hi; i += 256){
        const float* row = h2 + (size_t)i * C_OUT;
        #pragma unroll
        for (int c = 0; c < C_OUT; c++) acc[c] += row[c];
    }
    #pragma unroll
    for (int c = 0; c < C_OUT; c++){
        #pragma unroll
        for (int off = 32; off > 0; off >>= 1) acc[c] += __shfl_xor(acc[c], off, 64);
    }
    __shared__ float sd[4][C_OUT];
    int wave = threadIdx.x >> 6, lane = threadIdx.x & 63;
    if (lane == 0){
        #pragma unroll
        for (int c = 0; c < C_OUT; c++) sd[wave][c] = acc[c];
    }
    __syncthreads();
    if (threadIdx.x == 0){
        float cnt = (float)(hi - lo);
        if (cnt < 1.f) cnt = 1.f;
        float v[C_OUT];
        float m = -1e30f;
        #pragma unroll
        for (int c = 0; c < C_OUT; c++){
            v[c] = (sd[0][c] + sd[1][c] + sd[2][c] + sd[3][c]) / cnt;
            m = fmaxf(m, v[c]);
        }
        float sum = 0.f;
        #pragma unroll
        for (int c = 0; c < C_OUT; c++) sum += __expf(v[c] - m);
        float lse = m + __logf(sum);
        #pragma unroll
        for (int c = 0; c < C_OUT; c++) out[g * C_OUT + c] = v[c] - lse;
    }
}

extern "C" void kernel_launch(void* const* d_in, const int* in_sizes, int n_in,
                              void* d_out, int out_size, void* d_ws, size_t ws_size,
                              hipStream_t stream){
    const float* x    = (const float*)d_in[0];
    const int*   ei   = (const int*)d_in[1];
    const int*   batch= (const int*)d_in[2];
    const float* W1   = (const float*)d_in[3];
    const float* as1  = (const float*)d_in[4];
    const float* ad1  = (const float*)d_in[5];
    const float* b1   = (const float*)d_in[6];
    const float* W2   = (const float*)d_in[7];
    const float* as2v = (const float*)d_in[8];
    const float* ad2v = (const float*)d_in[9];
    const float* b2   = (const float*)d_in[10];
    float* out = (float*)d_out;

    char* ws = (char*)d_ws;
    size_t off = 0;
    auto alloc = [&](size_t bytes)->char*{
        char* p = ws + off;
        off = (off + bytes + 255) & ~(size_t)255;
        return p;
    };
    unsigned short* xhb  = (unsigned short*)alloc((size_t)N_NODES * HC * 2);   // 25.6 MB
    unsigned short* bt   = (unsigned short*)alloc((size_t)HC * 256 * 2);       // 131 KB [hi|lo]
    float* asc1 = (float*)alloc((size_t)N_NODES * NH * 4);
    float* adc1 = (float*)alloc((size_t)N_NODES * NH * 4);
    int*   deg  = (int*)alloc((size_t)N_NODES * 4);
    int*   rowp = (int*)alloc((size_t)(N_NODES + 1) * 4);
    int*   cur  = (int*)alloc((size_t)N_NODES * 4);
    int*   colb = (int*)alloc((size_t)E_TOT * 4);
    int*   bsum = (int*)alloc(64 * 4);
    int*   bexcl= (int*)alloc(64 * 4);
    float* xh2  = (float*)alloc((size_t)N_NODES * XSTRIDE * 4);                // 3.2 MB
    float* W2t  = (float*)alloc((size_t)HC * C_OUT * 4);
    float* h2   = (float*)alloc((size_t)N_NODES * C_OUT * 4);
    (void)ws_size; (void)in_sizes; (void)n_in; (void)out_size;

    hipMemsetAsync(deg, 0, (size_t)N_NODES * 4, stream);
    hipLaunchKernelGGL(k_setup,   dim3(NB_DEG + 129), dim3(256), 0, stream, ei, deg, W1, bt, W2, W2t);
    hipLaunchKernelGGL(k_gemm1m,  dim3(391),   dim3(256), 0, stream, x, bt, as1, ad1, xhb, asc1, adc1);
    hipLaunchKernelGGL(k_bsum,    dim3(NBLK),  dim3(256), 0, stream, deg, bsum);
    hipLaunchKernelGGL(k_scanb,   dim3(1),     dim3(64),  0, stream, bsum, bexcl, rowp);
    hipLaunchKernelGGL(k_scan,    dim3(NBLK),  dim3(1024),0, stream, deg, bexcl, rowp, cur);
    hipLaunchKernelGGL(k_scatter, dim3((E_TOT + 255)/256), dim3(256), 0, stream, ei, cur, colb);
    hipLaunchKernelGGL(k_agg1f,   dim3((N_NODES + 3)/4), dim3(256), 0, stream, xhb, asc1, adc1, rowp, colb, b1, W2t, as2v, ad2v, xh2);
    hipLaunchKernelGGL(k_agg2,    dim3((N_NODES + 15)/16), dim3(256), 0, stream, xh2, rowp, colb, b2, h2);
    hipLaunchKernelGGL(k_pool,    dim3(N_GRAPH), dim3(256), 0, stream, h2, batch, out);
}